// Round 11
// baseline (634.117 us; speedup 1.0000x reference)
//
#include <hip/hip_runtime.h>
#include <math.h>

namespace {

constexpr int T_ = 1024;
constexpr int HKV_ = 8;
constexpr int M_ = 8;
constexpr int D_ = 64;
constexpr int WIN_ = 128;
constexpr float SCALE_ = 0.125f;   // 1/sqrt(64)

constexpr int IB_ = 16;            // query rows per block (2 per wave)
constexpr int NKEY_ = 144;         // staged keys: [i0-127, i0+16]
constexpr int NTHREADS_ = 512;

using f4 = __attribute__((ext_vector_type(4))) float;

// Fully-resident grid: 512 blocks = exactly 2/CU (LDS 76.5KB, 2x512 thr).
// Removes the 4-sequential-batch store bubbles of the 1024-block version:
// one staging bubble at t=0, then the store stream runs uninterrupted.
// All R4-R10 lessons kept: plain cached f4 full-row stores (NT/partial-line
// => RMW tax), no global loads post-barrier (vmcnt shared with stores),
// no launch_bounds (VGPR cap => spill tax), f32 K+q in LDS (bf16-K unpack
// costs inner-loop VALU).
__global__ void attn_qk_softmax(const float* __restrict__ qg,
                                const float* __restrict__ kg,
                                const float* __restrict__ sinks,
                                float* __restrict__ outg)
{
    __shared__ float k_lds[NKEY_ * D_];        // XOR-swizzled key rows (36.9 KB)
    __shared__ float q_lds[IB_][M_ * D_];      // q rows, f32 (32.8 KB)
    __shared__ float p_lds[8][2][136];         // pad-17 probs, dbuf (8.7 KB)

    const int tid  = threadIdx.x;
    const int wave = tid >> 6;
    const int lane = tid & 63;
    const int h    = blockIdx.x / (T_ / IB_);
    const int i0   = (blockIdx.x % (T_ / IB_)) * IB_;
    const int base = i0 - (WIN_ - 1);          // global j of staged key r=0

    // ---- stage K window into LDS (swizzled: c4 ^= ((r>>1)&7)<<2) ----
    for (int f = tid; f < NKEY_ * (D_ / 4); f += NTHREADS_) {
        const int r  = f >> 4;
        const int c4 = (f & 15) << 2;
        const int j  = base + r;
        f4 v = {0.f, 0.f, 0.f, 0.f};
        if ((unsigned)j < (unsigned)T_)
            v = *reinterpret_cast<const f4*>(kg + ((size_t)j * HKV_ + h) * D_ + c4);
        const int sw = c4 ^ (((r >> 1) & 7) << 2);
        *reinterpret_cast<f4*>(&k_lds[r * D_ + sw]) = v;
    }
    // ---- stage all 16 q rows (f32, f4 chunks; 2048 chunks / 512 thr) ----
    for (int f = tid; f < IB_ * (M_ * D_ / 4); f += NTHREADS_) {
        const int row = f >> 7;                // 128 chunks per row
        const int off = (f & 127) << 2;
        *reinterpret_cast<f4*>(&q_lds[row][off]) =
            *reinterpret_cast<const f4*>(
                qg + ((size_t)(i0 + row) * HKV_ + h) * (M_ * D_) + off);
    }
    __syncthreads();

    // ---- two rows per wave: ia (even) and ib = ia+1 ----
    const int ia   = i0 + 2 * wave;
    const int ib   = ia + 1;
    const int jloA = (ia >= WIN_ - 1) ? (ia - (WIN_ - 1)) : 0;
    const int jloB = (ib >= WIN_ - 1) ? (ib - (WIN_ - 1)) : 0;
    const int cntA = ia - jloA + 1;
    const int cntB = ib - jloB + 1;
    const int rloA = jloA - base;
    const int rloB = jloB - base;

    const int idx0 = 2 * lane;
    const int idx1 = idx0 + 1;

    int r0A = rloA + idx0; if (r0A > NKEY_ - 1) r0A = NKEY_ - 1;
    int r1A = rloA + idx1; if (r1A > NKEY_ - 1) r1A = NKEY_ - 1;
    int r0B = rloB + idx0; if (r0B > NKEY_ - 1) r0B = NKEY_ - 1;
    int r1B = rloB + idx1; if (r1B > NKEY_ - 1) r1B = NKEY_ - 1;

    float accA0[M_], accA1[M_], accB0[M_], accB1[M_];
    #pragma unroll
    for (int m = 0; m < M_; ++m) {
        accA0[m] = 0.f; accA1[m] = 0.f; accB0[m] = 0.f; accB1[m] = 0.f;
    }

    const float* kA0 = &k_lds[r0A * D_];
    const float* kA1 = &k_lds[r1A * D_];
    const float* kB0 = &k_lds[r0B * D_];
    const float* kB1 = &k_lds[r1B * D_];
    const int swA0 = ((r0A >> 1) & 7) << 2;
    const int swA1 = ((r1A >> 1) & 7) << 2;
    const int swB0 = ((r0B >> 1) & 7) << 2;
    const int swB1 = ((r1B >> 1) & 7) << 2;

    const float* qA = q_lds[2 * wave];
    const float* qB = q_lds[2 * wave + 1];

    #pragma unroll
    for (int c = 0; c < 16; ++c) {
        const int c4 = c << 2;
        const f4 kvA0 = *reinterpret_cast<const f4*>(kA0 + (c4 ^ swA0));
        const f4 kvA1 = *reinterpret_cast<const f4*>(kA1 + (c4 ^ swA1));
        const f4 kvB0 = *reinterpret_cast<const f4*>(kB0 + (c4 ^ swB0));
        const f4 kvB1 = *reinterpret_cast<const f4*>(kB1 + (c4 ^ swB1));
        #pragma unroll
        for (int m = 0; m < M_; ++m) {
            const f4 qa = *reinterpret_cast<const f4*>(qA + m * D_ + c4);
            const f4 qb = *reinterpret_cast<const f4*>(qB + m * D_ + c4);
            accA0[m] = fmaf(qa.x, kvA0.x, accA0[m]);
            accA0[m] = fmaf(qa.y, kvA0.y, accA0[m]);
            accA0[m] = fmaf(qa.z, kvA0.z, accA0[m]);
            accA0[m] = fmaf(qa.w, kvA0.w, accA0[m]);
            accA1[m] = fmaf(qa.x, kvA1.x, accA1[m]);
            accA1[m] = fmaf(qa.y, kvA1.y, accA1[m]);
            accA1[m] = fmaf(qa.z, kvA1.z, accA1[m]);
            accA1[m] = fmaf(qa.w, kvA1.w, accA1[m]);
            accB0[m] = fmaf(qb.x, kvB0.x, accB0[m]);
            accB0[m] = fmaf(qb.y, kvB0.y, accB0[m]);
            accB0[m] = fmaf(qb.z, kvB0.z, accB0[m]);
            accB0[m] = fmaf(qb.w, kvB0.w, accB0[m]);
            accB1[m] = fmaf(qb.x, kvB1.x, accB1[m]);
            accB1[m] = fmaf(qb.y, kvB1.y, accB1[m]);
            accB1[m] = fmaf(qb.z, kvB1.z, accB1[m]);
            accB1[m] = fmaf(qb.w, kvB1.w, accB1[m]);
        }
    }

    // ---- per-row, per-m softmax (with sink) + full-row plain store ----
    #pragma unroll
    for (int rr = 0; rr < 2; ++rr) {
        const int   i    = rr ? ib   : ia;
        const int   jlo  = rr ? jloB : jloA;
        const int   cnt  = rr ? cntB : cntA;
        const float* ac0 = rr ? accB0 : accA0;
        const float* ac1 = rr ? accB1 : accA1;
        const bool  v0   = idx0 < cnt;
        const bool  v1   = idx1 < cnt;

        #pragma unroll
        for (int m = 0; m < M_; ++m) {
            float l0 = v0 ? ac0[m] * SCALE_ : -INFINITY;
            float l1 = v1 ? ac1[m] * SCALE_ : -INFINITY;
            float mx = fmaxf(l0, l1);
            #pragma unroll
            for (int s = 1; s < 64; s <<= 1)
                mx = fmaxf(mx, __shfl_xor(mx, s, 64));
            const float slog = sinks[h * M_ + m];
            mx = fmaxf(mx, slog);
            float p0 = __expf(l0 - mx);        // exp(-inf)=0 for masked keys
            float p1 = __expf(l1 - mx);
            float sum = p0 + p1;
            #pragma unroll
            for (int s = 1; s < 64; s <<= 1)
                sum += __shfl_xor(sum, s, 64);
            const float inv = 1.0f / (sum + __expf(slog - mx));
            p0 *= inv;
            p1 *= inv;

            float* pb = p_lds[wave][m & 1];    // double buffer
            pb[idx0 + (idx0 >> 4)] = p0;
            pb[idx1 + (idx1 >> 4)] = p1;
            asm volatile("s_waitcnt lgkmcnt(0)" ::: "memory");

            // Full 4 KB row, 4 plain f4 stores/lane; each instruction covers
            // 1 KB contiguous = 8 full 128B lines from this wave alone.
            float* orow = outg + (((size_t)(h * M_ + m) * T_ + i) * T_);
            #pragma unroll
            for (int t = 0; t < 4; ++t) {
                const int j = t * 256 + lane * 4;
                f4 ov;
                #pragma unroll
                for (int u = 0; u < 4; ++u) {
                    int idx = j + u - jlo;
                    const bool in = (unsigned)idx < (unsigned)cnt;
                    int ci = idx; if (ci < 0) ci = 0; if (ci > 127) ci = 127;
                    const float val = pb[ci + (ci >> 4)];
                    ov[u] = in ? val : 0.0f;
                }
                *reinterpret_cast<f4*>(orow + j) = ov;   // plain cached store
            }
        }
    }
}

} // namespace

extern "C" void kernel_launch(void* const* d_in, const int* in_sizes, int n_in,
                              void* d_out, int out_size, void* d_ws, size_t ws_size,
                              hipStream_t stream) {
    const float* q     = (const float*)d_in[0];
    const float* k     = (const float*)d_in[1];
    const float* sinks = (const float*)d_in[2];
    float* out         = (float*)d_out;

    dim3 grid(HKV_ * (T_ / IB_));   // 8 heads * 64 i-blocks = 512 blocks (2/CU)
    attn_qk_softmax<<<grid, NTHREADS_, 0, stream>>>(q, k, sinks, out);
}

// Round 13
// 53.629 us; speedup vs baseline: 11.8241x; 11.8241x over previous
//
#include <hip/hip_runtime.h>
#include <math.h>

namespace {

constexpr int T_ = 1024;
constexpr int HKV_ = 8;
constexpr int M_ = 8;
constexpr int D_ = 64;
constexpr int WIN_ = 128;
constexpr float SCALE_ = 0.125f;   // 1/sqrt(64)

constexpr int IB_ = 8;             // query rows per block (1 per wave)
constexpr int NKEY_ = 136;         // staged keys: [i0-127, i0+8]
constexpr int NTHREADS_ = 512;

using f4 = __attribute__((ext_vector_type(4))) float;

// float -> bf16 (round-nearest-even), packed pair
__device__ inline unsigned bf16rne_pack(float x, float y) {
    unsigned bx = __float_as_uint(x);
    unsigned by = __float_as_uint(y);
    bx = (bx + 0x7FFFu + ((bx >> 16) & 1u)) >> 16;
    by = (by + 0x7FFFu + ((by >> 16) & 1u)) >> 16;
    return bx | (by << 16);
}

// ---- wave64 reductions on the VALU pipe (DPP), not the DS pipe ----
// rocPRIM sequence: row_shr 1,2,4,8 reduce each 16-lane row onto its top
// lane; row_bcast:15 folds row0->row1 (and row2->row3); row_bcast:31 folds
// rows 0-1 -> rows 2-3; lane 63 then holds the full-wave reduce; readlane.
template <int CTRL>
__device__ inline float dpp_max_step(float x) {
    // bound_ctrl=0, old=x: lanes with no source keep x -> fmax(x,x)=x
    int yi = __builtin_amdgcn_update_dpp(__float_as_int(x), __float_as_int(x),
                                         CTRL, 0xF, 0xF, false);
    return fmaxf(x, __int_as_float(yi));
}
template <int CTRL>
__device__ inline float dpp_add_step(float x) {
    // bound_ctrl=1: lanes with no source read 0 -> x += 0
    int yi = __builtin_amdgcn_update_dpp(0, __float_as_int(x),
                                         CTRL, 0xF, 0xF, true);
    return x + __int_as_float(yi);
}
__device__ inline float wave_max64(float x) {
    x = dpp_max_step<0x111>(x);   // row_shr:1
    x = dpp_max_step<0x112>(x);   // row_shr:2
    x = dpp_max_step<0x114>(x);   // row_shr:4
    x = dpp_max_step<0x118>(x);   // row_shr:8
    x = dpp_max_step<0x142>(x);   // row_bcast:15
    x = dpp_max_step<0x143>(x);   // row_bcast:31
    return __int_as_float(__builtin_amdgcn_readlane(__float_as_int(x), 63));
}
__device__ inline float wave_sum64(float x) {
    x = dpp_add_step<0x111>(x);
    x = dpp_add_step<0x112>(x);
    x = dpp_add_step<0x114>(x);
    x = dpp_add_step<0x118>(x);
    x = dpp_add_step<0x142>(x);
    x = dpp_add_step<0x143>(x);
    return __int_as_float(__builtin_amdgcn_readlane(__float_as_int(x), 63));
}

// Round-9 structure (55.5us champion, clean counters) with exactly ONE
// change: both softmax wave reductions moved from __shfl_xor (ds_swizzle,
// DS pipe, ~30cy/step) to DPP (VALU pipe, ~4cy/step). Epilogue DS-pipe ops
// drop ~40%, and the dependent-latency chain per (m,row) shrinks ~5x.
// Kept lessons: plain cached f4 full-row stores; no global loads
// post-barrier; no launch_bounds; no runtime-selected pointers to locals.
__global__ void attn_qk_softmax(const float* __restrict__ qg,
                                const float* __restrict__ kg,
                                const float* __restrict__ sinks,
                                float* __restrict__ outg)
{
    __shared__ float    k_lds[NKEY_ * D_];       // XOR-swizzled keys (34.8 KB)
    __shared__ unsigned q_lds[IB_][M_ * D_ / 2]; // bf16-packed q rows (8 KB)
    __shared__ float    p_lds[IB_][2][136];      // pad-17 probs, dbuf (8.7 KB)

    const int tid  = threadIdx.x;
    const int wave = tid >> 6;
    const int lane = tid & 63;
    const int h    = blockIdx.x / (T_ / IB_);
    const int i0   = (blockIdx.x % (T_ / IB_)) * IB_;
    const int base = i0 - (WIN_ - 1);            // global j of staged key r=0

    // ---- stage K window into LDS (swizzled: c4 ^= ((r>>1)&7)<<2) ----
    for (int f = tid; f < NKEY_ * (D_ / 4); f += NTHREADS_) {
        const int r  = f >> 4;
        const int c4 = (f & 15) << 2;
        const int j  = base + r;
        f4 v = {0.f, 0.f, 0.f, 0.f};
        if ((unsigned)j < (unsigned)T_)
            v = *reinterpret_cast<const f4*>(kg + ((size_t)j * HKV_ + h) * D_ + c4);
        const int sw = c4 ^ (((r >> 1) & 7) << 2);
        *reinterpret_cast<f4*>(&k_lds[r * D_ + sw]) = v;
    }
    // ---- stage this wave's q rows as packed bf16 ----
    {
        const int i = i0 + wave;
        const float* qp = qg + ((size_t)i * HKV_ + h) * (M_ * D_);
        const int off = lane * 4;                // float index within the row
        const f4 a = *reinterpret_cast<const f4*>(qp + off);
        const f4 b = *reinterpret_cast<const f4*>(qp + off + 256);
        uint2 pa, pb2;
        pa.x  = bf16rne_pack(a.x, a.y);
        pa.y  = bf16rne_pack(a.z, a.w);
        pb2.x = bf16rne_pack(b.x, b.y);
        pb2.y = bf16rne_pack(b.z, b.w);
        *reinterpret_cast<uint2*>(&q_lds[wave][off / 2])         = pa;
        *reinterpret_cast<uint2*>(&q_lds[wave][(off + 256) / 2]) = pb2;
    }
    __syncthreads();

    const int i   = i0 + wave;
    const int jlo = (i >= WIN_ - 1) ? (i - (WIN_ - 1)) : 0;
    const int cnt = i - jlo + 1;                 // 1..128 valid keys
    const int rlo = jlo - base;                  // rel idx of first valid key

    const int idx0 = 2 * lane;
    const int idx1 = idx0 + 1;
    const bool v0 = idx0 < cnt;
    const bool v1 = idx1 < cnt;
    int r0 = rlo + idx0; if (r0 > NKEY_ - 1) r0 = NKEY_ - 1;
    int r1 = rlo + idx1; if (r1 > NKEY_ - 1) r1 = NKEY_ - 1;

    float acc0[M_], acc1[M_];
    #pragma unroll
    for (int m = 0; m < M_; ++m) { acc0[m] = 0.f; acc1[m] = 0.f; }

    const float* k0p = &k_lds[r0 * D_];
    const float* k1p = &k_lds[r1 * D_];
    const int sw0 = ((r0 >> 1) & 7) << 2;
    const int sw1 = ((r1 >> 1) & 7) << 2;

    #pragma unroll
    for (int c = 0; c < 16; ++c) {
        const int c4 = c << 2;
        const f4 kv0 = *reinterpret_cast<const f4*>(k0p + (c4 ^ sw0));
        const f4 kv1 = *reinterpret_cast<const f4*>(k1p + (c4 ^ sw1));
        #pragma unroll
        for (int m = 0; m < M_; ++m) {
            // wave-uniform broadcast read of 4 bf16-packed q values (8B)
            const uint2 qw = *reinterpret_cast<const uint2*>(
                &q_lds[wave][(m * D_ + c4) / 2]);
            const float q0 = __uint_as_float(qw.x << 16);
            const float q1 = __uint_as_float(qw.x & 0xFFFF0000u);
            const float q2 = __uint_as_float(qw.y << 16);
            const float q3 = __uint_as_float(qw.y & 0xFFFF0000u);
            acc0[m] = fmaf(q0, kv0.x, acc0[m]);
            acc0[m] = fmaf(q1, kv0.y, acc0[m]);
            acc0[m] = fmaf(q2, kv0.z, acc0[m]);
            acc0[m] = fmaf(q3, kv0.w, acc0[m]);
            acc1[m] = fmaf(q0, kv1.x, acc1[m]);
            acc1[m] = fmaf(q1, kv1.y, acc1[m]);
            acc1[m] = fmaf(q2, kv1.z, acc1[m]);
            acc1[m] = fmaf(q3, kv1.w, acc1[m]);
        }
    }

    // ---- per-m softmax (with sink, DPP reduces) + full-row plain store ----
    #pragma unroll
    for (int m = 0; m < M_; ++m) {
        float l0 = v0 ? acc0[m] * SCALE_ : -INFINITY;
        float l1 = v1 ? acc1[m] * SCALE_ : -INFINITY;
        float mx = wave_max64(fmaxf(l0, l1));    // VALU-pipe reduce
        const float slog = sinks[h * M_ + m];
        mx = fmaxf(mx, slog);
        float p0 = __expf(l0 - mx);              // exp(-inf)=0 for masked keys
        float p1 = __expf(l1 - mx);
        const float sum = wave_sum64(p0 + p1);   // VALU-pipe reduce
        const float inv = 1.0f / (sum + __expf(slog - mx));
        p0 *= inv;
        p1 *= inv;

        float* pb = p_lds[wave][m & 1];          // double buffer
        pb[idx0 + (idx0 >> 4)] = p0;
        pb[idx1 + (idx1 >> 4)] = p1;
        asm volatile("s_waitcnt lgkmcnt(0)" ::: "memory");  // writes visible

        // Full 4 KB row, 4 plain f4 stores per lane; each instruction covers
        // 1 KB contiguous = 8 full 128B lines sourced entirely from this wave.
        float* orow = outg + (((size_t)(h * M_ + m) * T_ + i) * T_);
        #pragma unroll
        for (int t = 0; t < 4; ++t) {
            const int j = t * 256 + lane * 4;    // float index in row
            f4 ov;
            #pragma unroll
            for (int u = 0; u < 4; ++u) {
                int idx = j + u - jlo;
                const bool in = (unsigned)idx < (unsigned)cnt;
                int ci = idx; if (ci < 0) ci = 0; if (ci > 127) ci = 127;
                const float val = pb[ci + (ci >> 4)];
                ov[u] = in ? val : 0.0f;
            }
            *reinterpret_cast<f4*>(orow + j) = ov;   // plain cached store
        }
    }
}

} // namespace

extern "C" void kernel_launch(void* const* d_in, const int* in_sizes, int n_in,
                              void* d_out, int out_size, void* d_ws, size_t ws_size,
                              hipStream_t stream) {
    const float* q     = (const float*)d_in[0];
    const float* k     = (const float*)d_in[1];
    const float* sinks = (const float*)d_in[2];
    float* out         = (float*)d_out;

    dim3 grid(HKV_ * (T_ / IB_));   // 8 heads * 128 i-blocks = 1024 blocks
    attn_qk_softmax<<<grid, NTHREADS_, 0, stream>>>(q, k, sinks, out);
}